// Round 2
// baseline (285.238 us; speedup 1.0000x reference)
//
#include <hip/hip_runtime.h>

// QuantizedLinear: out[64,11008] = x[64,4096] @ (Wq*scale)^T + bias
// v3: single fused GEMM. x pre-converted to bf16 in d_ws (512 KB, L2-resident);
// A-fragments read directly from L2 (no LDS staging, no main-loop syncthreads).
// 4 waves/block split K (1024 each), one-time LDS cross-wave reduce fuses
// scale+bias+store. HBM: 180 MB weight stream (floor ~28 us) + 3.3 MB else.
// NOTE (round-1 counters): measured dur_us includes ~210 us of harness reset
// (688 MiB poison fills at 85% HBM peak); our kernels are the remaining ~50 us.

#define M_DIM 64
#define N_DIM 11008
#define K_DIM 4096
#define BLOCK_N 16
#define NBLOCKS (N_DIM / BLOCK_N)   // 688
#define KW (K_DIM / 4)              // 1024 k per wave

typedef __attribute__((ext_vector_type(8))) short bf16x8;
typedef __attribute__((ext_vector_type(8))) short s16x8;
typedef __attribute__((ext_vector_type(4))) float f32x4;
typedef __attribute__((ext_vector_type(4))) int i32x4;
typedef __attribute__((ext_vector_type(4))) short s16x4;

// int in [-128,127] -> bf16 is EXACT: cvt to f32 then truncate mantissa
__device__ __forceinline__ short i2bf(int q) {
    float f = (float)q;
    return (short)(__builtin_bit_cast(unsigned int, f) >> 16);
}

// RNE float -> bf16
__device__ __forceinline__ short f2bf(float f) {
    unsigned int u = __builtin_bit_cast(unsigned int, f);
    u = u + 0x7FFFu + ((u >> 16) & 1u);
    return (short)(u >> 16);
}

// ---- x f32 -> bf16, once. 262144 elems, 8/thread, 128 blocks. ----
__global__ __launch_bounds__(256) void xcvt_kernel(const float* __restrict__ x,
                                                   short* __restrict__ xbf) {
    int idx = (blockIdx.x * 256 + threadIdx.x) * 8;
    f32x4 a = *(const f32x4*)(x + idx);
    f32x4 b = *(const f32x4*)(x + idx + 4);
    s16x8 h;
    h[0] = f2bf(a.x); h[1] = f2bf(a.y); h[2] = f2bf(a.z); h[3] = f2bf(a.w);
    h[4] = f2bf(b.x); h[5] = f2bf(b.y); h[6] = f2bf(b.z); h[7] = f2bf(b.w);
    *(s16x8*)(xbf + idx) = h;
}

// ---- fused GEMM: one block per 16 output columns; waves split K ----
__global__ __launch_bounds__(256) void qlinear_fused_kernel(const short* __restrict__ xbf,
                                                            const int* __restrict__ wq,
                                                            const float* __restrict__ scale_p,
                                                            const float* __restrict__ bias,
                                                            float* __restrict__ out) {
    __shared__ float red[4][M_DIM][BLOCK_N];   // 16 KB, used once at the end

    const int tid  = threadIdx.x;
    const int wave = tid >> 6;
    const int lane = tid & 63;
    const int quad = lane >> 4;
    const int l16  = lane & 15;

    const int n0 = blockIdx.x * BLOCK_N;
    const int k0 = wave * KW;

    // B: weight row (n0+l16), 8 consecutive int32 at k = k0 + kk + quad*8
    const int*   bptr = wq  + (size_t)(n0 + l16) * K_DIM + k0 + quad * 8;
    // A: x row l16 (+ mi*16), 8 consecutive bf16 at the same k
    const short* aptr = xbf + (size_t)l16 * K_DIM + k0 + quad * 8;

    f32x4 acc[4] = {f32x4{0,0,0,0}, f32x4{0,0,0,0}, f32x4{0,0,0,0}, f32x4{0,0,0,0}};

    #pragma unroll 4
    for (int kk = 0; kk < KW; kk += 32) {
        i32x4 b0 = *(const i32x4*)(bptr + kk);
        i32x4 b1 = *(const i32x4*)(bptr + kk + 4);
        bf16x8 bfrag;
        bfrag[0] = i2bf(b0.x); bfrag[1] = i2bf(b0.y);
        bfrag[2] = i2bf(b0.z); bfrag[3] = i2bf(b0.w);
        bfrag[4] = i2bf(b1.x); bfrag[5] = i2bf(b1.y);
        bfrag[6] = i2bf(b1.z); bfrag[7] = i2bf(b1.w);

        #pragma unroll
        for (int mi = 0; mi < 4; ++mi) {
            bf16x8 afrag = *(const bf16x8*)(aptr + (size_t)mi * 16 * K_DIM + kk);
            acc[mi] = __builtin_amdgcn_mfma_f32_16x16x32_bf16(afrag, bfrag, acc[mi], 0, 0, 0);
        }
    }

    // ---- cross-wave K reduction via LDS, fused scale+bias+store ----
    #pragma unroll
    for (int mi = 0; mi < 4; ++mi) {
        #pragma unroll
        for (int r = 0; r < 4; ++r) {
            red[wave][mi * 16 + quad * 4 + r][l16] = acc[mi][r];
        }
    }
    __syncthreads();

    {
        const float scale = *scale_p;
        int idx = tid * 4;          // 0..1020 over 64x16 tile
        int m = idx >> 4;
        int n = idx & 15;           // 0,4,8,12
        f32x4 s0 = *(const f32x4*)&red[0][m][n];
        f32x4 s1 = *(const f32x4*)&red[1][m][n];
        f32x4 s2 = *(const f32x4*)&red[2][m][n];
        f32x4 s3 = *(const f32x4*)&red[3][m][n];
        f32x4 bb = *(const f32x4*)(bias + n0 + n);
        f32x4 r;
        r.x = (s0.x + s1.x + s2.x + s3.x) * scale + bb.x;
        r.y = (s0.y + s1.y + s2.y + s3.y) * scale + bb.y;
        r.z = (s0.z + s1.z + s2.z + s3.z) * scale + bb.z;
        r.w = (s0.w + s1.w + s2.w + s3.w) * scale + bb.w;
        *(f32x4*)(out + (size_t)m * N_DIM + n0 + n) = r;
    }
}

// ---------------------------------------------------------------------------
// Fallback (verified round-0 path) if ws is unusable: bias-init + atomic GEMM.
// ---------------------------------------------------------------------------

#define KSPLIT 8
#define KC (K_DIM / KSPLIT)
#define BK 128
#define LDS_STRIDE 136
#define FB_BLOCK_N 64

__global__ __launch_bounds__(256) void init_bias_kernel(const float* __restrict__ bias,
                                                        float* __restrict__ out) {
    int idx = blockIdx.x * 256 + threadIdx.x;
    int col4 = idx % 2752;
    f32x4 b = *(const f32x4*)(bias + col4 * 4);
    *(f32x4*)(out + (size_t)idx * 4) = b;
}

__global__ __launch_bounds__(256) void qlinear_atomic_kernel(const float* __restrict__ x,
                                                             const int* __restrict__ wq,
                                                             const float* __restrict__ scale_p,
                                                             float* __restrict__ out) {
    __shared__ short lds[M_DIM * LDS_STRIDE];

    const int tid  = threadIdx.x;
    const int wave = tid >> 6;
    const int lane = tid & 63;
    const int quad = lane >> 4;
    const int l16  = lane & 15;

    const int n0  = blockIdx.x * FB_BLOCK_N;
    const int kc0 = blockIdx.y * KC;
    const float scale = *scale_p;

    const int nw = n0 + wave * 16 + l16;
    const int* wptr = wq + (size_t)nw * K_DIM + kc0 + quad * 8;

    f32x4 acc[4] = {f32x4{0,0,0,0}, f32x4{0,0,0,0}, f32x4{0,0,0,0}, f32x4{0,0,0,0}};

    for (int kb = 0; kb < KC; kb += BK) {
        {
            const float* xbase = x + kc0 + kb;
            #pragma unroll
            for (int j = 0; j < 8; ++j) {
                int f  = tid + j * 256;
                int row = f >> 5;
                int c4  = f & 31;
                f32x4 v = *(const f32x4*)(xbase + (size_t)row * K_DIM + c4 * 4);
                s16x4 h;
                h.x = f2bf(v.x); h.y = f2bf(v.y); h.z = f2bf(v.z); h.w = f2bf(v.w);
                *(s16x4*)&lds[row * LDS_STRIDE + c4 * 4] = h;
            }
        }
        __syncthreads();

        #pragma unroll
        for (int kk = 0; kk < BK; kk += 32) {
            i32x4 b0 = *(const i32x4*)(wptr + kb + kk);
            i32x4 b1 = *(const i32x4*)(wptr + kb + kk + 4);
            bf16x8 bfrag;
            bfrag[0] = i2bf(b0.x); bfrag[1] = i2bf(b0.y);
            bfrag[2] = i2bf(b0.z); bfrag[3] = i2bf(b0.w);
            bfrag[4] = i2bf(b1.x); bfrag[5] = i2bf(b1.y);
            bfrag[6] = i2bf(b1.z); bfrag[7] = i2bf(b1.w);

            #pragma unroll
            for (int mi = 0; mi < 4; ++mi) {
                bf16x8 afrag = *(const bf16x8*)&lds[(mi * 16 + l16) * LDS_STRIDE + kk + quad * 8];
                acc[mi] = __builtin_amdgcn_mfma_f32_16x16x32_bf16(afrag, bfrag, acc[mi], 0, 0, 0);
            }
        }
        __syncthreads();
    }

    const int nout = n0 + wave * 16 + l16;
    #pragma unroll
    for (int mi = 0; mi < 4; ++mi) {
        #pragma unroll
        for (int r = 0; r < 4; ++r) {
            int m = mi * 16 + quad * 4 + r;
            atomicAdd(&out[(size_t)m * N_DIM + nout], acc[mi][r] * scale);
        }
    }
}

extern "C" void kernel_launch(void* const* d_in, const int* in_sizes, int n_in,
                              void* d_out, int out_size, void* d_ws, size_t ws_size,
                              hipStream_t stream) {
    const float* x      = (const float*)d_in[0];
    const int*   wq     = (const int*)d_in[1];
    const float* scale  = (const float*)d_in[2];
    const float* bias   = (const float*)d_in[3];
    float* out = (float*)d_out;

    const size_t xbf_bytes = (size_t)M_DIM * K_DIM * sizeof(short);  // 512 KB

    if (ws_size >= xbf_bytes && d_ws != nullptr) {
        short* xbf = (short*)d_ws;
        // 1) x -> bf16 once (262144 elems, 8/thread)
        xcvt_kernel<<<(M_DIM * K_DIM) / (256 * 8), 256, 0, stream>>>(x, xbf);
        // 2) fused GEMM: 688 blocks, no main-loop syncs, direct final store
        qlinear_fused_kernel<<<NBLOCKS, 256, 0, stream>>>(xbf, wq, scale, bias, out);
    } else {
        // Fallback: verified atomic path
        init_bias_kernel<<<688, 256, 0, stream>>>(bias, out);
        dim3 grid(N_DIM / FB_BLOCK_N, KSPLIT);
        qlinear_atomic_kernel<<<grid, 256, 0, stream>>>(x, wq, scale, out);
    }
}

// Round 3
// 258.959 us; speedup vs baseline: 1.1015x; 1.1015x over previous
//
#include <hip/hip_runtime.h>

// QuantizedLinear: out[64,11008] = x[64,4096] @ (Wq*scale)^T + bias
// v4: m97-structure GEMM. Weight stream (180 MB int32) staged HBM->LDS via
// global_load_lds (width 16) for deep vmcnt queue (~48 KB in flight per block,
// 3 blocks/CU) instead of 8x16B reg loads (~2.7 KB/CU -> latency-limited
// ~2.4 TB/s, the round-0..2 bottleneck). x pre-converted to bf16 (d_ws) and
// also gload_lds-staged. LDS reads XOR-swizzled (byte ^= (row&7)<<4) with the
// inverse swizzle applied to the per-lane GLOBAL source addresses (linear LDS
// dest is a gload_lds HW requirement). Epilogue: bias-init + atomicAdd
// (measured cheap at 5.6M atomics in rounds 0-2).
//
// Model from round-1/2 counters: dur_us = ~180 us fixed harness reset
// (688 MiB poison fill @ 85% HBM peak + input restore) + our kernels.
// v0/v2 ours ~80 us; v4 target ~37 us (weight stream at ~6 TB/s).

#define M_DIM 64
#define N_DIM 11008
#define K_DIM 4096
#define KSPLIT 8
#define KC (K_DIM / KSPLIT)   // 512
#define BK 128                // k per staged tile
#define BLOCK_N 64            // 4 waves x 16 N each

typedef __attribute__((ext_vector_type(8))) short bf16x8;
typedef __attribute__((ext_vector_type(8))) short s16x8;
typedef __attribute__((ext_vector_type(4))) float f32x4;
typedef __attribute__((ext_vector_type(4))) int i32x4;
typedef __attribute__((ext_vector_type(4))) short s16x4;

// int in [-128,127] -> bf16 is EXACT: cvt to f32, truncate mantissa
__device__ __forceinline__ short i2bf(int q) {
    float f = (float)q;
    return (short)(__builtin_bit_cast(unsigned int, f) >> 16);
}

// RNE float -> bf16
__device__ __forceinline__ short f2bf(float f) {
    unsigned int u = __builtin_bit_cast(unsigned int, f);
    u = u + 0x7FFFu + ((u >> 16) & 1u);
    return (short)(u >> 16);
}

// async global->LDS, 16 B per lane. LDS dest: wave-uniform base + lane*16
// (linear). Global src is per-lane.
__device__ __forceinline__ void load_lds_16B(const void* g, void* l) {
    __builtin_amdgcn_global_load_lds(
        (const __attribute__((address_space(1))) unsigned int*)g,
        (__attribute__((address_space(3))) unsigned int*)l,
        16, 0, 0);
}

// ---- x f32 -> bf16, once (512 KB into d_ws). 262144 elems, 8/thread. ----
__global__ __launch_bounds__(256) void xcvt_kernel(const float* __restrict__ x,
                                                   short* __restrict__ xbf) {
    int idx = (blockIdx.x * 256 + threadIdx.x) * 8;
    f32x4 a = *(const f32x4*)(x + idx);
    f32x4 b = *(const f32x4*)(x + idx + 4);
    s16x8 h;
    h[0] = f2bf(a.x); h[1] = f2bf(a.y); h[2] = f2bf(a.z); h[3] = f2bf(a.w);
    h[4] = f2bf(b.x); h[5] = f2bf(b.y); h[6] = f2bf(b.z); h[7] = f2bf(b.w);
    *(s16x8*)(xbf + idx) = h;
}

// ---- out = bias broadcast (atomic GEMM accumulates on top) ----
__global__ __launch_bounds__(256) void init_bias_kernel(const float* __restrict__ bias,
                                                        float* __restrict__ out) {
    int idx = blockIdx.x * 256 + threadIdx.x;
    int col4 = idx % 2752;               // N/4
    f32x4 b = *(const f32x4*)(bias + col4 * 4);
    *(f32x4*)(out + (size_t)idx * 4) = b;
}

// ---- v4 GEMM: gload_lds-staged weights + x, swizzled LDS, atomic K-split ----
__global__ __launch_bounds__(256) void qlinear_v4_kernel(const short* __restrict__ xbf,
                                                         const int* __restrict__ wq,
                                                         const float* __restrict__ scale_p,
                                                         float* __restrict__ out) {
    // LDS: weights 64 rows x 512 B (128 int32) = 32768 B, then x 64 rows x 256 B
    // (128 bf16) = 16384 B. 49152 B total -> 3 blocks/CU.
    __shared__ char smem[49152];
    char* wlds = smem;            // [row][512 B], XOR-swizzled by (row&7)<<4
    char* xlds = smem + 32768;    // [row][256 B], XOR-swizzled by (row&7)<<4

    const int tid  = threadIdx.x;
    const int wave = tid >> 6;
    const int lane = tid & 63;
    const int quad = lane >> 4;
    const int l16  = lane & 15;

    const int n0  = blockIdx.x * BLOCK_N;
    const int kc0 = blockIdx.y * KC;
    const float scale = *scale_p;

    f32x4 acc[4] = {f32x4{0,0,0,0}, f32x4{0,0,0,0}, f32x4{0,0,0,0}, f32x4{0,0,0,0}};

    for (int kb = 0; kb < KC; kb += BK) {
        // ---- stage: issue 12 gload_lds per wave (8 weight + 4 x), 48 KB/block ----
        // Weights: instr j covers rows (wave*16 + j*2) + {0,1}; 32 lanes per row,
        // each lane 16 B. Source col pre-swizzled so swizzled READ sees logical data.
        #pragma unroll
        for (int j = 0; j < 8; ++j) {
            int row  = wave * 16 + j * 2 + (lane >> 5);
            int colb = ((lane & 31) * 16) ^ ((row & 7) << 4);
            const char* g = (const char*)(wq + (size_t)(n0 + row) * K_DIM + kc0 + kb) + colb;
            load_lds_16B(g, wlds + (wave * 16 + j * 2) * 512);
        }
        // x (bf16): instr j covers rows (wave*16 + j*4) + {0..3}; 16 lanes per row.
        #pragma unroll
        for (int j = 0; j < 4; ++j) {
            int row  = wave * 16 + j * 4 + (lane >> 4);
            int colb = ((lane & 15) * 16) ^ ((row & 7) << 4);
            const char* g = (const char*)(xbf + (size_t)row * K_DIM + kc0 + kb) + colb;
            load_lds_16B(g, xlds + (wave * 16 + j * 4) * 256);
        }
        __syncthreads();   // drains vmcnt; other resident blocks compute meanwhile

        // ---- compute: 4 k-steps of 32 ----
        #pragma unroll
        for (int kk = 0; kk < BK; kk += 32) {
            const int wrow = wave * 16 + l16;
            const int wsw  = (wrow & 7) << 4;
            const int L0   = (kk + quad * 8) * 4;              // logical byte in 512B row
            i32x4 b0 = *(const i32x4*)(wlds + wrow * 512 + ((L0)      ^ wsw));
            i32x4 b1 = *(const i32x4*)(wlds + wrow * 512 + ((L0 + 16) ^ wsw));
            bf16x8 bfrag;
            bfrag[0] = i2bf(b0.x); bfrag[1] = i2bf(b0.y);
            bfrag[2] = i2bf(b0.z); bfrag[3] = i2bf(b0.w);
            bfrag[4] = i2bf(b1.x); bfrag[5] = i2bf(b1.y);
            bfrag[6] = i2bf(b1.z); bfrag[7] = i2bf(b1.w);

            #pragma unroll
            for (int mi = 0; mi < 4; ++mi) {
                const int arow = mi * 16 + l16;
                const int La   = (kk + quad * 8) * 2;          // logical byte in 256B row
                bf16x8 afrag = *(const bf16x8*)(xlds + arow * 256 + (La ^ ((arow & 7) << 4)));
                acc[mi] = __builtin_amdgcn_mfma_f32_16x16x32_bf16(afrag, bfrag, acc[mi], 0, 0, 0);
            }
        }
        __syncthreads();   // LDS reuse barrier
    }

    // ---- epilogue: scale + atomic accumulate (K-split partials) ----
    const int nout = n0 + wave * 16 + l16;
    #pragma unroll
    for (int mi = 0; mi < 4; ++mi) {
        #pragma unroll
        for (int r = 0; r < 4; ++r) {
            int m = mi * 16 + quad * 4 + r;
            atomicAdd(&out[(size_t)m * N_DIM + nout], acc[mi][r] * scale);
        }
    }
}

// ---------------------------------------------------------------------------
// Fallback (round-0 verified): reg-loaded weights + LDS-staged x + atomics.
// Used only if d_ws can't hold the 512 KB bf16 x.
// ---------------------------------------------------------------------------
#define LDS_STRIDE 136

__global__ __launch_bounds__(256) void qlinear_atomic_kernel(const float* __restrict__ x,
                                                             const int* __restrict__ wq,
                                                             const float* __restrict__ scale_p,
                                                             float* __restrict__ out) {
    __shared__ short lds[M_DIM * LDS_STRIDE];

    const int tid  = threadIdx.x;
    const int wave = tid >> 6;
    const int lane = tid & 63;
    const int quad = lane >> 4;
    const int l16  = lane & 15;

    const int n0  = blockIdx.x * BLOCK_N;
    const int kc0 = blockIdx.y * KC;
    const float scale = *scale_p;

    const int nw = n0 + wave * 16 + l16;
    const int* wptr = wq + (size_t)nw * K_DIM + kc0 + quad * 8;

    f32x4 acc[4] = {f32x4{0,0,0,0}, f32x4{0,0,0,0}, f32x4{0,0,0,0}, f32x4{0,0,0,0}};

    for (int kb = 0; kb < KC; kb += BK) {
        {
            const float* xbase = x + kc0 + kb;
            #pragma unroll
            for (int j = 0; j < 8; ++j) {
                int f  = tid + j * 256;
                int row = f >> 5;
                int c4  = f & 31;
                f32x4 v = *(const f32x4*)(xbase + (size_t)row * K_DIM + c4 * 4);
                s16x4 h;
                h.x = f2bf(v.x); h.y = f2bf(v.y); h.z = f2bf(v.z); h.w = f2bf(v.w);
                *(s16x4*)&lds[row * LDS_STRIDE + c4 * 4] = h;
            }
        }
        __syncthreads();

        #pragma unroll
        for (int kk = 0; kk < BK; kk += 32) {
            i32x4 b0 = *(const i32x4*)(wptr + kb + kk);
            i32x4 b1 = *(const i32x4*)(wptr + kb + kk + 4);
            bf16x8 bfrag;
            bfrag[0] = i2bf(b0.x); bfrag[1] = i2bf(b0.y);
            bfrag[2] = i2bf(b0.z); bfrag[3] = i2bf(b0.w);
            bfrag[4] = i2bf(b1.x); bfrag[5] = i2bf(b1.y);
            bfrag[6] = i2bf(b1.z); bfrag[7] = i2bf(b1.w);

            #pragma unroll
            for (int mi = 0; mi < 4; ++mi) {
                bf16x8 afrag = *(const bf16x8*)&lds[(mi * 16 + l16) * LDS_STRIDE + kk + quad * 8];
                acc[mi] = __builtin_amdgcn_mfma_f32_16x16x32_bf16(afrag, bfrag, acc[mi], 0, 0, 0);
            }
        }
        __syncthreads();
    }

    const int nout = n0 + wave * 16 + l16;
    #pragma unroll
    for (int mi = 0; mi < 4; ++mi) {
        #pragma unroll
        for (int r = 0; r < 4; ++r) {
            int m = mi * 16 + quad * 4 + r;
            atomicAdd(&out[(size_t)m * N_DIM + nout], acc[mi][r] * scale);
        }
    }
}

extern "C" void kernel_launch(void* const* d_in, const int* in_sizes, int n_in,
                              void* d_out, int out_size, void* d_ws, size_t ws_size,
                              hipStream_t stream) {
    const float* x      = (const float*)d_in[0];
    const int*   wq     = (const int*)d_in[1];
    const float* scale  = (const float*)d_in[2];
    const float* bias   = (const float*)d_in[3];
    float* out = (float*)d_out;

    const size_t xbf_bytes = (size_t)M_DIM * K_DIM * sizeof(short);  // 512 KB
    dim3 grid(N_DIM / BLOCK_N, KSPLIT);  // (172, 8)

    if (ws_size >= xbf_bytes && d_ws != nullptr) {
        short* xbf = (short*)d_ws;
        xcvt_kernel<<<(M_DIM * K_DIM) / (256 * 8), 256, 0, stream>>>(x, xbf);
        init_bias_kernel<<<688, 256, 0, stream>>>(bias, out);
        qlinear_v4_kernel<<<grid, 256, 0, stream>>>(xbf, wq, scale, out);
    } else {
        init_bias_kernel<<<688, 256, 0, stream>>>(bias, out);
        qlinear_atomic_kernel<<<grid, 256, 0, stream>>>(x, wq, scale, out);
    }
}